// Round 9
// baseline (4705.212 us; speedup 1.0000x reference)
//
#include <hip/hip_runtime.h>
#include <stdint.h>

typedef unsigned int u32;
typedef unsigned long long u64;
typedef __attribute__((ext_vector_type(8))) short short8;
typedef __attribute__((ext_vector_type(4))) float f32x4;

#define NN 8192
#define DD 512
#define CC 64            // NUM_CENTROIDS
#define RR 5             // NUM_KMEANS
#define KM_ITERS 20
#define TOPKK 16
#define CHUNK 4096       // sim row-chunk (134 MB -> L3-resident)
#define GAP_TH 0.05f     // assign: f32 gap below which we re-decide in f64
#define FLAGTH 0.02f     // topk: margin16-17 below which row is resolved exactly
#define BAND_TH 0.01f    // resolve: band half-width around val16
#define TK_LO 256.0f     // linear bins cover [-256, 256) in steps of 1/8
#define TK_SCALE 8.0f
#define FIXG 4           // fixup flags batched per block pass (centD reuse)

#define MFMA_BF16 __builtin_amdgcn_mfma_f32_16x16x32_bf16

// async global->LDS, 16B per lane; LDS dest = wave-uniform base + lane*16.
__device__ __forceinline__ void gload16(void* lds, const void* g) {
  __builtin_amdgcn_global_load_lds(
      (const __attribute__((address_space(1))) void*)g,
      (__attribute__((address_space(3))) void*)lds, 16, 0, 0);
}

// monotone key encode (exact total order on floats, desc-select by max)
__device__ __forceinline__ u32 keyenc(float v) {
  u32 u = __float_as_uint(v);
  return (u & 0x80000000u) ? ~u : (u | 0x80000000u);
}
// monotone linear bin; clamp keeps it monotone for out-of-range values
__device__ __forceinline__ int tkbin(float v) {
  int b = (int)((v + TK_LO) * TK_SCALE);
  return b < 0 ? 0 : (b > 4095 ? 4095 : b);
}

// ---------------- Threefry-2x32, 20 rounds (matches jax/_src/prng.py) -------
__device__ __forceinline__ void tf2x32(u32 k0, u32 k1, u32 x0, u32 x1,
                                       u32& o0, u32& o1) {
  u32 ks2 = k0 ^ k1 ^ 0x1BD11BDAu;
  x0 += k0; x1 += k1;
#define TFR(r) { x0 += x1; x1 = (x1 << r) | (x1 >> (32 - r)); x1 ^= x0; }
  TFR(13) TFR(15) TFR(26) TFR(6)
  x0 += k1; x1 += ks2 + 1u;
  TFR(17) TFR(29) TFR(16) TFR(24)
  x0 += ks2; x1 += k0 + 2u;
  TFR(13) TFR(15) TFR(26) TFR(6)
  x0 += k0; x1 += k1 + 3u;
  TFR(17) TFR(29) TFR(16) TFR(24)
  x0 += k1; x1 += ks2 + 4u;
  TFR(13) TFR(15) TFR(26) TFR(6)
  x0 += ks2; x1 += k0 + 5u;
#undef TFR
  o0 = x0; o1 = x1;
}

__global__ __launch_bounds__(256) void rng_kernel(u32* __restrict__ bits1,
                                                  u32* __restrict__ bits2) {
  int r = blockIdx.x;
  int i = blockIdx.y * 256 + threadIdx.x;
  u32 rk0, rk1; tf2x32(0u, 1234u, 0u, (u32)r, rk0, rk1);
  u32 k10, k11, s10, s11, s20, s21;
  tf2x32(rk0, rk1, 0u, 0u, k10, k11);
  tf2x32(rk0, rk1, 0u, 1u, s10, s11);
  tf2x32(k10, k11, 0u, 1u, s20, s21);
  u32 a, b;
  tf2x32(s10, s11, 0u, (u32)i, a, b);
  bits1[r * NN + i] = a ^ b;
  tf2x32(s20, s21, 0u, (u32)i, a, b);
  bits2[r * NN + i] = a ^ b;
}

__global__ __launch_bounds__(256) void rankpart_kernel(const u32* __restrict__ bits,
                                                       u32* __restrict__ prank) {
  __shared__ u64 sk[2048];
  int r = blockIdx.x, zc = blockIdx.z;
  const u32* bb = bits + (size_t)r * NN;
  int jbase = zc * 2048;
  for (int t = threadIdx.x; t < 2048; t += 256)
    sk[t] = ((u64)bb[jbase + t] << 13) | (u32)(jbase + t);
  __syncthreads();
  int i = blockIdx.y * 256 + threadIdx.x;
  u64 ki = ((u64)bb[i] << 13) | (u32)i;
  int cnt = 0;
#pragma unroll 8
  for (int j = 0; j < 2048; ++j) cnt += (int)(sk[j] < ki);
  prank[(size_t)(r * 4 + zc) * NN + i] = cnt;
}

__global__ __launch_bounds__(256) void scat1_kernel(const u32* __restrict__ prank,
                                                    int* __restrict__ vout) {
  int r = blockIdx.x;
  int i = blockIdx.y * 256 + threadIdx.x;
  int rank = prank[(size_t)(r * 4 + 0) * NN + i] + prank[(size_t)(r * 4 + 1) * NN + i] +
             prank[(size_t)(r * 4 + 2) * NN + i] + prank[(size_t)(r * 4 + 3) * NN + i];
  vout[(size_t)r * NN + rank] = i;
}

__global__ __launch_bounds__(256) void scat2_kernel(const u32* __restrict__ prank,
                                                    const int* __restrict__ v1,
                                                    int* __restrict__ sel) {
  int r = blockIdx.x;
  int i = blockIdx.y * 256 + threadIdx.x;
  int rank = prank[(size_t)(r * 4 + 0) * NN + i] + prank[(size_t)(r * 4 + 1) * NN + i] +
             prank[(size_t)(r * 4 + 2) * NN + i] + prank[(size_t)(r * 4 + 3) * NN + i];
  if (rank < CC) sel[r * CC + rank] = v1[(size_t)r * NN + i];
}

__device__ __forceinline__ double block_reduce_d(double s, double* red4) {
  int tid = threadIdx.x;
  for (int off = 32; off > 0; off >>= 1) s += __shfl_down(s, off, 64);
  if ((tid & 63) == 0) red4[tid >> 6] = s;
  __syncthreads();
  return red4[0] + red4[1] + red4[2] + red4[3];
}

// -------- bf16 split helpers --------
__device__ __forceinline__ u32 bf16rne(float a) {
  u32 ab = __float_as_uint(a);
  return (ab + 0x7FFFu + ((ab >> 16) & 1u)) >> 16;
}
__device__ __forceinline__ void splitf(float a, unsigned short& hi, unsigned short& lo) {
  u32 h = bf16rne(a);
  float hf = __uint_as_float(h << 16);
  hi = (unsigned short)h;
  lo = (unsigned short)bf16rne(a - hf);
}

// init centroids: f64 copy + norms + fused bf16 hi/lo split.
__global__ __launch_bounds__(256) void init_cent_kernel(const float* __restrict__ X,
                                                        const int* __restrict__ sel,
                                                        double* __restrict__ centD,
                                                        double* __restrict__ cnD,
                                                        float* __restrict__ cnF,
                                                        unsigned short* __restrict__ CHg,
                                                        unsigned short* __restrict__ CLg) {
  __shared__ double red4[4];
  int r = blockIdx.x, c = blockIdx.y, t = threadIdx.x;
  int src = sel[r * CC + c];
  const float* xp = X + (size_t)src * DD;
  size_t o = (size_t)(r * CC + c) * DD;
  double va = (double)xp[t], vb = (double)xp[t + 256];
  centD[o + t] = va; centD[o + t + 256] = vb;
  unsigned short h0, l0, h1, l1;
  splitf((float)va, h0, l0); splitf((float)vb, h1, l1);
  CHg[o + t] = h0; CLg[o + t] = l0;
  CHg[o + t + 256] = h1; CLg[o + t + 256] = l1;
  double tot = block_reduce_d(va * va + vb * vb, red4);
  if (t == 0) { cnD[r * CC + c] = tot; cnF[r * CC + c] = (float)tot; }
}

// Split an f32 array into hi/lo bf16 arrays. 8 elements per thread. (S/T only.)
__global__ __launch_bounds__(256) void split_kernel(const float* __restrict__ in,
                                                    unsigned short* __restrict__ hi,
                                                    unsigned short* __restrict__ lo) {
  size_t base = ((size_t)blockIdx.x * 256 + threadIdx.x) * 8;
  float4 v0 = *(const float4*)(in + base);
  float4 v1 = *(const float4*)(in + base + 4);
  float vv[8] = {v0.x, v0.y, v0.z, v0.w, v1.x, v1.y, v1.z, v1.w};
  unsigned short h[8], l[8];
#pragma unroll
  for (int j = 0; j < 8; ++j) splitf(vv[j], h[j], l[j]);
  uint4 hv, lv;
  hv.x = h[0] | ((u32)h[1] << 16); hv.y = h[2] | ((u32)h[3] << 16);
  hv.z = h[4] | ((u32)h[5] << 16); hv.w = h[6] | ((u32)h[7] << 16);
  lv.x = l[0] | ((u32)l[1] << 16); lv.y = l[2] | ((u32)l[3] << 16);
  lv.z = l[4] | ((u32)l[5] << 16); lv.w = l[6] | ((u32)l[7] << 16);
  *(uint4*)(hi + base) = hv;
  *(uint4*)(lo + base) = lv;
}

// MFMA assign: BK=64, global_load_lds staging. Labels + PER-R flag lists.
__global__ __launch_bounds__(256) void assign_kernel(const unsigned short* __restrict__ XH,
                                                     const unsigned short* __restrict__ XL,
                                                     const unsigned short* __restrict__ CHg,
                                                     const unsigned short* __restrict__ CLg,
                                                     const float* __restrict__ cnF,
                                                     int* __restrict__ labels,
                                                     u32* __restrict__ flags,
                                                     u32* __restrict__ counters) {
  __shared__ unsigned short Xh[2 * 64 * 32], Xl[2 * 64 * 32],
                            Ch[2 * 64 * 32], Cl[2 * 64 * 32];
  __shared__ float dmat[64 * 68];
  int r = blockIdx.y;
  int blk = blockIdx.x;
  int rowBase = blk * 64;
  int tid = threadIdx.x;
  int wid = tid >> 6, lane = tid & 63, m = lane & 15, q = lane >> 4;
  int srow = wid * 16 + (lane >> 2);
  int sslot = (lane & 3) * 8;                 // in shorts
  const unsigned short* gxh = XH + (size_t)(rowBase + srow) * DD + sslot;
  const unsigned short* gxl = XL + (size_t)(rowBase + srow) * DD + sslot;
  const unsigned short* gch = CHg + ((size_t)r * CC + srow) * DD + sslot;
  const unsigned short* gcl = CLg + ((size_t)r * CC + srow) * DD + sslot;
  f32x4 acc[4] = {};
  for (int kc = 0; kc < DD; kc += 64) {
#pragma unroll
    for (int p = 0; p < 2; ++p) {
      int off = p * 2048, ko = kc + p * 32;
      gload16(&Xh[off + wid * 512], gxh + ko);
      gload16(&Xl[off + wid * 512], gxl + ko);
      gload16(&Ch[off + wid * 512], gch + ko);
      gload16(&Cl[off + wid * 512], gcl + ko);
    }
    __syncthreads();
#pragma unroll
    for (int s = 0; s < 2; ++s) {
      int off = s * 2048;
      short8 ah = *(short8*)&Xh[off + (wid * 16 + m) * 32 + q * 8];
      short8 al = *(short8*)&Xl[off + (wid * 16 + m) * 32 + q * 8];
#pragma unroll
      for (int nt = 0; nt < 4; ++nt) {
        short8 bh = *(short8*)&Ch[off + (nt * 16 + m) * 32 + q * 8];
        short8 bl = *(short8*)&Cl[off + (nt * 16 + m) * 32 + q * 8];
        acc[nt] = MFMA_BF16(ah, bh, acc[nt], 0, 0, 0);
        acc[nt] = MFMA_BF16(ah, bl, acc[nt], 0, 0, 0);
        acc[nt] = MFMA_BF16(al, bh, acc[nt], 0, 0, 0);
      }
    }
    __syncthreads();
  }
#pragma unroll
  for (int nt = 0; nt < 4; ++nt) {
    float cn = cnF[r * CC + nt * 16 + m];
#pragma unroll
    for (int reg = 0; reg < 4; ++reg)
      dmat[(wid * 16 + q * 4 + reg) * 68 + nt * 16 + m] = cn - 2.0f * acc[nt][reg];
  }
  __syncthreads();
  if (tid < 64) {
    const float* dr = dmat + (size_t)tid * 68;
    float best = dr[0], second = 3.4e38f; int bi = 0;
    for (int c = 1; c < CC; ++c) {
      float v = dr[c];
      if (v < best) { second = best; best = v; bi = c; }
      else if (v < second) second = v;
    }
    labels[(size_t)r * NN + rowBase + tid] = bi;
    if (second - best < GAP_TH) {
      u32 idx = atomicAdd(counters + r, 1u);      // per-r counter (<= NN always)
      flags[(size_t)r * NN + idx] = (u32)(rowBase + tid);
    }
  }
}

// Exact f64 re-decision, per-r lists, FIXG flags batched per block pass:
// each centD element is loaded once and reused for FIXG independent chains.
// Per-flag arithmetic order identical to the unbatched version.
__global__ __launch_bounds__(256) void fixup_kernel(const float* __restrict__ X,
                                                    const double* __restrict__ centD,
                                                    const double* __restrict__ cnD,
                                                    const u32* __restrict__ flags,
                                                    const u32* __restrict__ counters,
                                                    int* __restrict__ labels) {
  __shared__ double darr[FIXG][CC];
  int r = blockIdx.y;
  int n = (int)counters[r];
  int tid = threadIdx.x, c = tid >> 2, sub = tid & 3;
  const u32* fl = flags + (size_t)r * NN;
  for (int f0 = blockIdx.x * FIXG; f0 < n; f0 += gridDim.x * FIXG) {
    int nb = n - f0; if (nb > FIXG) nb = FIXG;
    const float* x[FIXG];
    int ii[FIXG];
#pragma unroll
    for (int g = 0; g < FIXG; ++g) {
      int gi = g < nb ? (int)fl[f0 + g] : (int)fl[f0];   // dup first if short
      ii[g] = gi;
      x[g] = X + (size_t)gi * DD + sub * 128;
    }
    const double* cp = centD + (size_t)(r * CC + c) * DD + sub * 128;
    double s[FIXG] = {0.0, 0.0, 0.0, 0.0};
    for (int k = 0; k < 128; ++k) {
      double cpv = cp[k];
#pragma unroll
      for (int g = 0; g < FIXG; ++g) s[g] += (double)x[g][k] * cpv;
    }
#pragma unroll
    for (int g = 0; g < FIXG; ++g) {
      s[g] += __shfl_down(s[g], 2, 64);
      s[g] += __shfl_down(s[g], 1, 64);
    }
    if (sub == 0) {
      double cn = cnD[r * CC + c];
#pragma unroll
      for (int g = 0; g < FIXG; ++g) darr[g][c] = cn - 2.0 * s[g];
    }
    __syncthreads();
    if (tid < nb) {
      double best = darr[tid][0]; int bi = 0;
      for (int cc = 1; cc < CC; ++cc) {
        double v = darr[tid][cc];
        if (v < best) { best = v; bi = cc; }
      }
      labels[(size_t)r * NN + ii[tid]] = bi;
    }
    __syncthreads();
  }
}

// Per-64-row-group histogram + rank-in-group from corrected labels.
__global__ __launch_bounds__(64) void hist_kernel(const int* __restrict__ labels,
                                                  int* __restrict__ bhist,
                                                  int* __restrict__ rib) {
  __shared__ int labs[64];
  __shared__ int h[CC];
  int r = blockIdx.y, blk = blockIdx.x, tid = threadIdx.x;
  labs[tid] = labels[(size_t)r * NN + blk * 64 + tid];
  h[tid] = 0;
  __syncthreads();
  int lab = labs[tid];
  atomicAdd(&h[lab], 1);
  int rk = 0;
  for (int j = 0; j < tid; ++j) rk += (labs[j] == lab);
  rib[(size_t)r * NN + blk * 64 + tid] = rk;
  __syncthreads();
  bhist[(size_t)(r * 128 + blk) * CC + tid] = h[tid];
}

// fill fused with scan.
__global__ __launch_bounds__(256) void fill_kernel(const int* __restrict__ labels,
                                                   const int* __restrict__ rib,
                                                   const int* __restrict__ bhist,
                                                   int* __restrict__ cstart,
                                                   int* __restrict__ cnt,
                                                   int* __restrict__ member) {
  __shared__ int bh[128 * CC];
  __shared__ int cs[CC];
  __shared__ int tots[CC];
  int r = blockIdx.x, blk = blockIdx.y, tid = threadIdx.x;
  const int* src = bhist + (size_t)r * 128 * CC;
  for (int t = tid; t < 128 * CC; t += 256) bh[t] = src[t];
  __syncthreads();
  if (tid < CC) {
    int run = 0;
    for (int b = 0; b < 128; ++b) { int v = bh[b * CC + tid]; bh[b * CC + tid] = run; run += v; }
    tots[tid] = run;
  }
  __syncthreads();
  if (tid == 0) {
    int run = 0;
    for (int q2 = 0; q2 < CC; ++q2) { cs[q2] = run; run += tots[q2]; }
  }
  __syncthreads();
  int i = blk * 256 + tid;
  int lab = labels[(size_t)r * NN + i];
  int pos = cs[lab] + bh[(i >> 6) * CC + lab] + rib[(size_t)r * NN + i];
  member[(size_t)r * NN + pos] = i;
  if (blk == 0 && tid < CC) { cnt[r * CC + tid] = tots[tid]; cstart[r * CC + tid] = cs[tid]; }
}

__global__ __launch_bounds__(256) void update_kernel(const float* __restrict__ X,
                                                     const int* __restrict__ member,
                                                     const int* __restrict__ cstart,
                                                     const int* __restrict__ cnt,
                                                     const double* __restrict__ centOld,
                                                     double* __restrict__ centNew) {
  __shared__ double part[4][64];
  int r = blockIdx.x, c = blockIdx.y, dchunk = blockIdx.z;
  int tid = threadIdx.x;
  int d = dchunk * 64 + (tid & 63);
  int lane = tid >> 6;
  int n = cnt[r * CC + c];
  int st = cstart[r * CC + c];
  const int* mem = member + (size_t)r * NN + st;
  int n4 = (n + 3) >> 2;
  int lo = lane * n4;
  int hi = min(n, lo + n4);
  double s0 = 0, s1 = 0, s2 = 0, s3 = 0;
  int m = lo;
  for (; m + 3 < hi; m += 4) {
    s0 += (double)X[(size_t)mem[m + 0] * DD + d];
    s1 += (double)X[(size_t)mem[m + 1] * DD + d];
    s2 += (double)X[(size_t)mem[m + 2] * DD + d];
    s3 += (double)X[(size_t)mem[m + 3] * DD + d];
  }
  for (; m < hi; ++m) s0 += (double)X[(size_t)mem[m] * DD + d];
  part[lane][tid & 63] = (s0 + s1) + (s2 + s3);
  __syncthreads();
  if (tid < 64) {
    double tot = (part[0][tid] + part[1][tid]) + (part[2][tid] + part[3][tid]);
    size_t o = (size_t)(r * CC + c) * DD + dchunk * 64 + tid;
    double va = (n > 0) ? tot / (double)n : centOld[o];
    centNew[o] = va;
  }
}

// norm fused with centroid bf16 split.
__global__ __launch_bounds__(256) void norm_kernel(const double* __restrict__ centNew,
                                                   double* __restrict__ cnD,
                                                   float* __restrict__ cnF,
                                                   unsigned short* __restrict__ CHg,
                                                   unsigned short* __restrict__ CLg) {
  __shared__ double red4[4];
  int r = blockIdx.x, c = blockIdx.y, t = threadIdx.x;
  size_t o = (size_t)(r * CC + c) * DD;
  double va = centNew[o + t], vb = centNew[o + t + 256];
  unsigned short h0, l0, h1, l1;
  splitf((float)va, h0, l0); splitf((float)vb, h1, l1);
  CHg[o + t] = h0; CLg[o + t] = l0;
  CHg[o + t + 256] = h1; CLg[o + t + 256] = l1;
  double tot = block_reduce_d(va * va + vb * vb, red4);
  if (t == 0) { cnD[r * CC + c] = tot; cnF[r * CC + c] = (float)tot; }
}

// MFMA sim GEMM: 128x128 tile, 4 waves 2x2, bf16x3, BK=64,
// global_load_lds staging, bijective XCD swizzle.
__global__ __launch_bounds__(256) void gemm_kernel(const unsigned short* __restrict__ SH,
                                                   const unsigned short* __restrict__ SL,
                                                   const unsigned short* __restrict__ TH,
                                                   const unsigned short* __restrict__ TL,
                                                   float* __restrict__ sim,
                                                   int rowChunk) {
  __shared__ unsigned short Ah[2 * 128 * 32], Al[2 * 128 * 32],
                            Bh[2 * 128 * 32], Bl[2 * 128 * 32];
  int tid = threadIdx.x;
  int wid = tid >> 6, lane = tid & 63, m = lane & 15, q = lane >> 4;
  int waveM = wid >> 1, waveN = wid & 1;
  const int nwgx = NN / 128;                  // 64
  const int nwg = nwgx * (CHUNK / 128);       // 2048 (divisible by 8)
  int wg = blockIdx.y * nwgx + blockIdx.x;
  int swz = (wg & 7) * (nwg >> 3) + (wg >> 3);
  int rowTile = swz / nwgx, colTile = swz % nwgx;
  int rowBase = rowChunk + rowTile * 128;
  int colBase = colTile * 128;
  int sr0 = wid * 16 + (lane >> 2);
  int sr1 = (wid + 4) * 16 + (lane >> 2);
  int sslot = (lane & 3) * 8;                 // shorts
  const unsigned short* gah0 = SH + (size_t)(rowBase + sr0) * DD + sslot;
  const unsigned short* gah1 = SH + (size_t)(rowBase + sr1) * DD + sslot;
  const unsigned short* gal0 = SL + (size_t)(rowBase + sr0) * DD + sslot;
  const unsigned short* gal1 = SL + (size_t)(rowBase + sr1) * DD + sslot;
  const unsigned short* gbh0 = TH + (size_t)(colBase + sr0) * DD + sslot;
  const unsigned short* gbh1 = TH + (size_t)(colBase + sr1) * DD + sslot;
  const unsigned short* gbl0 = TL + (size_t)(colBase + sr0) * DD + sslot;
  const unsigned short* gbl1 = TL + (size_t)(colBase + sr1) * DD + sslot;
  f32x4 acc[4][4] = {};
  for (int kc = 0; kc < DD; kc += 64) {
#pragma unroll
    for (int p = 0; p < 2; ++p) {
      int off = p * 4096, ko = kc + p * 32;
      gload16(&Ah[off + wid * 512], gah0 + ko);
      gload16(&Ah[off + (wid + 4) * 512], gah1 + ko);
      gload16(&Al[off + wid * 512], gal0 + ko);
      gload16(&Al[off + (wid + 4) * 512], gal1 + ko);
      gload16(&Bh[off + wid * 512], gbh0 + ko);
      gload16(&Bh[off + (wid + 4) * 512], gbh1 + ko);
      gload16(&Bl[off + wid * 512], gbl0 + ko);
      gload16(&Bl[off + (wid + 4) * 512], gbl1 + ko);
    }
    __syncthreads();
#pragma unroll
    for (int s = 0; s < 2; ++s) {
      int off = s * 4096;
      short8 ah[4], al[4], bh[4], bl[4];
#pragma unroll
      for (int t = 0; t < 4; ++t) {
        ah[t] = *(short8*)&Ah[off + (waveM * 64 + t * 16 + m) * 32 + q * 8];
        al[t] = *(short8*)&Al[off + (waveM * 64 + t * 16 + m) * 32 + q * 8];
        bh[t] = *(short8*)&Bh[off + (waveN * 64 + t * 16 + m) * 32 + q * 8];
        bl[t] = *(short8*)&Bl[off + (waveN * 64 + t * 16 + m) * 32 + q * 8];
      }
#pragma unroll
      for (int mt = 0; mt < 4; ++mt)
#pragma unroll
        for (int nt = 0; nt < 4; ++nt) {
          acc[mt][nt] = MFMA_BF16(ah[mt], bh[nt], acc[mt][nt], 0, 0, 0);
          acc[mt][nt] = MFMA_BF16(ah[mt], bl[nt], acc[mt][nt], 0, 0, 0);
          acc[mt][nt] = MFMA_BF16(al[mt], bh[nt], acc[mt][nt], 0, 0, 0);
        }
    }
    __syncthreads();
  }
#pragma unroll
  for (int mt = 0; mt < 4; ++mt)
#pragma unroll
    for (int nt = 0; nt < 4; ++nt) {
      int gcol = colBase + waveN * 64 + nt * 16 + m;
#pragma unroll
      for (int reg = 0; reg < 4; ++reg) {
        int lrow = rowTile * 128 + waveM * 64 + mt * 16 + q * 4 + reg;
        int grow = rowChunk + lrow;
        float v = acc[mt][nt][reg];
        if (grow == gcol) v += 10.0f;
        sim[(size_t)lrow * NN + gcol] = v;
      }
    }
}

// ---- top-16 via single-level LINEAR-bin select + fused exact resolve.
__global__ __launch_bounds__(256) void topk_kernel(const float* __restrict__ sim,
                                                   const float* __restrict__ S,
                                                   const float* __restrict__ T,
                                                   int* __restrict__ iknn,
                                                   int rowChunk) {
  __shared__ int bins[4096];      // 16 KB
  __shared__ int partial[256];
  __shared__ u64 cand[128];
  __shared__ u64 sure[24];        // provably <=16 used
  __shared__ u64 outk[TOPKK + 1];
  __shared__ u64 red[4];
  __shared__ int nsure, ncand, selB1, hardcase;
  __shared__ int nsureR, nbandR;
  __shared__ int sidx[16];
  __shared__ int bidx[64];
  __shared__ double bval[64];

  int blk = blockIdx.x, tid = threadIdx.x;
  int grow = rowChunk + blk;
  const float* rp = sim + (size_t)blk * NN;

  for (int t = tid; t < 4096; t += 256) bins[t] = 0;
  if (tid == 0) { nsure = 0; ncand = 0; hardcase = 0; }
  __syncthreads();
  for (int t = tid; t < NN; t += 256) atomicAdd(&bins[tkbin(rp[t])], 1);
  __syncthreads();
  int ps = 0;
#pragma unroll
  for (int b = 0; b < 16; ++b) ps += bins[tid * 16 + b];
  partial[tid] = ps;
  __syncthreads();
  if (tid == 0) {
    int cum = 0, c = 255;
    for (; c > 0; --c) { if (cum + partial[c] >= 17) break; cum += partial[c]; }
    int b = c * 16 + 15;
    for (; b > c * 16; --b) { if (cum + bins[b] >= 17) break; cum += bins[b]; }
    selB1 = b;
  }
  __syncthreads();
  int B1 = selB1;
  for (int t = tid; t < NN; t += 256) {
    float v = rp[t];
    int b = tkbin(v);
    if (b < B1) continue;
    u64 key = ((u64)keyenc(v) << 32) | (u32)(NN - 1 - t);
    if (b > B1) { int s = atomicAdd(&nsure, 1); if (s < 24) sure[s] = key; }
    else        { int s = atomicAdd(&ncand, 1); if (s < 128) cand[s] = key; }
  }
  __syncthreads();
  if (tid == 0 && ncand > 128) hardcase = 1;
  __syncthreads();
  if (!hardcase) {
    int ns = nsure, nc = ncand;
    int total = ns + nc;
    if (tid < total) {
      u64 k = tid < ns ? sure[tid] : cand[tid - ns];
      int rank = 0;
      for (int j = 0; j < total; ++j) {
        u64 o = j < ns ? sure[j] : cand[j - ns];
        rank += (int)(o > k);
      }
      if (rank < TOPKK + 1) outk[rank] = k;
    }
    __syncthreads();
  } else {
    for (int k = 0; k < TOPKK + 1; ++k) {
      u64 best = 0;
      for (int t = tid; t < NN; t += 256) {
        u64 key = ((u64)keyenc(rp[t]) << 32) | (u32)(NN - 1 - t);
        bool excl = false;
        for (int j = 0; j < k; ++j) excl |= (outk[j] == key);
        if (!excl && key > best) best = key;
      }
      for (int off = 32; off > 0; off >>= 1) {
        u32 lo = (u32)best, hi = (u32)(best >> 32);
        lo = __shfl_down(lo, off, 64); hi = __shfl_down(hi, off, 64);
        u64 o = ((u64)hi << 32) | lo;
        best = o > best ? o : best;
      }
      if ((tid & 63) == 0) red[tid >> 6] = best;
      __syncthreads();
      if (tid == 0) {
        u64 b = red[0];
        for (int w = 1; w < 4; ++w) b = red[w] > b ? red[w] : b;
        outk[k] = b;
      }
      __syncthreads();
    }
  }
  if (tid < TOPKK)
    iknn[(size_t)grow * TOPKK + tid] = (NN - 1) - (int)(outk[tid] & 0xFFFFFFFFu);
  u32 ub16 = (u32)(outk[TOPKK - 1] >> 32), ub17 = (u32)(outk[TOPKK] >> 32);
  float v16 = (ub16 & 0x80000000u) ? __uint_as_float(ub16 & 0x7FFFFFFFu)
                                   : __uint_as_float(~ub16);
  float v17 = (ub17 & 0x80000000u) ? __uint_as_float(ub17 & 0x7FFFFFFFu)
                                   : __uint_as_float(~ub17);
  if (v16 - v17 >= FLAGTH) return;

  // ---- fused exact resolve (marginal rows only; same math as before) ----
  if (tid == 0) { nsureR = 0; nbandR = 0; }
  __syncthreads();
  for (int j = tid; j < NN; j += 256) {
    float v = rp[j];
    if (v > v16 + BAND_TH) {
      int s = atomicAdd(&nsureR, 1);
      if (s < 16) sidx[s] = j;
    } else if (v >= v16 - BAND_TH) {
      int s = atomicAdd(&nbandR, 1);
      if (s < 64) bidx[s] = j;
    }
  }
  __syncthreads();
  int nb = nbandR > 64 ? 64 : nbandR;
  if (tid < nb) {
    const float* sp = S + (size_t)grow * DD;
    const float* tp = T + (size_t)bidx[tid] * DD;
    double s = 0.0;
    for (int k = 0; k < DD; ++k) s += (double)sp[k] * (double)tp[k];
    bval[tid] = s;
  }
  __syncthreads();
  if (tid == 0) {
    int w = 0;
    int ns = nsureR < 16 ? nsureR : 16;
    for (int i2 = 0; i2 < ns; ++i2) iknn[(size_t)grow * TOPKK + w++] = sidx[i2];
    u64 used = 0;
    while (w < TOPKK) {
      int bj = -1; double bv = 0.0;
      for (int i2 = 0; i2 < nb; ++i2) {
        if (used & (1ull << i2)) continue;
        if (bj < 0 || bval[i2] > bv ||
            (bval[i2] == bv && bidx[i2] < bidx[bj])) { bv = bval[i2]; bj = i2; }
      }
      if (bj < 0) break;
      used |= 1ull << bj;
      iknn[(size_t)grow * TOPKK + w++] = bidx[bj];
    }
  }
}

__global__ __launch_bounds__(256) void zero_kernel(float4* __restrict__ out) {
  size_t i = (size_t)blockIdx.x * 256 + threadIdx.x;
  out[i] = make_float4(0.f, 0.f, 0.f, 0.f);
}

__global__ void zeroc_kernel(u32* __restrict__ c) {
  c[threadIdx.x] = 0u;   // 128 counters: (KM_ITERS+1) x RR = 105 used
}

__global__ __launch_bounds__(256) void scatter_kernel(const float* __restrict__ adj,
                                                      const int* __restrict__ iknn,
                                                      const int* __restrict__ labels,
                                                      float* __restrict__ out) {
  int idx = blockIdx.x * 256 + threadIdx.x;
  int i = idx >> 4;
  int col = iknn[idx];
  int m = 0;
#pragma unroll
  for (int r = 0; r < RR; ++r)
    m |= (labels[(size_t)r * NN + i] == labels[(size_t)r * NN + col]);
  size_t o = (size_t)i * NN + col;
  out[o] = adj[o] + (float)m;
}

extern "C" void kernel_launch(void* const* d_in, const int* in_sizes, int n_in,
                              void* d_out, int out_size, void* d_ws, size_t ws_size,
                              hipStream_t stream) {
  (void)in_sizes; (void)n_in; (void)out_size; (void)ws_size;
  const float* adj     = (const float*)d_in[0];
  const float* student = (const float*)d_in[1];
  const float* teacher = (const float*)d_in[2];
  float* out = (float*)d_out;

  char* p = (char*)d_ws;
  auto alloc = [&](size_t bytes) -> void* {
    void* q = (void*)p; p += (bytes + 255) & ~(size_t)255; return q;
  };
  double* centA  = (double*)alloc((size_t)RR * CC * DD * 8);
  double* centB  = (double*)alloc((size_t)RR * CC * DD * 8);
  double* cnD    = (double*)alloc((size_t)RR * CC * 8);
  float*  cnF    = (float*) alloc((size_t)RR * CC * 4);
  u32*    bits1  = (u32*)   alloc((size_t)RR * NN * 4);
  u32*    bits2  = (u32*)   alloc((size_t)RR * NN * 4);
  u32*    prank  = (u32*)   alloc((size_t)RR * 4 * NN * 4);
  int*    v1     = (int*)   alloc((size_t)RR * NN * 4);
  int*    sel    = (int*)   alloc((size_t)RR * CC * 4);
  int*    labels = (int*)   alloc((size_t)RR * NN * 4);
  int*    bhist  = (int*)   alloc((size_t)RR * 128 * CC * 4);
  int*    cstart = (int*)   alloc((size_t)RR * CC * 4);
  int*    cnt    = (int*)   alloc((size_t)RR * CC * 4);
  int*    rib    = (int*)   alloc((size_t)RR * NN * 4);
  int*    member = (int*)   alloc((size_t)RR * NN * 4);
  u32*    flags  = (u32*)   alloc((size_t)RR * NN * 4);
  u32*    counters = (u32*) alloc((size_t)128 * 4);
  int*    iknn   = (int*)   alloc((size_t)NN * TOPKK * 4);
  unsigned short* SH = (unsigned short*)alloc((size_t)NN * DD * 2);
  unsigned short* SL = (unsigned short*)alloc((size_t)NN * DD * 2);
  unsigned short* THi = (unsigned short*)alloc((size_t)NN * DD * 2);
  unsigned short* TLo = (unsigned short*)alloc((size_t)NN * DD * 2);
  unsigned short* CHg = (unsigned short*)alloc((size_t)RR * CC * DD * 2);
  unsigned short* CLg = (unsigned short*)alloc((size_t)RR * CC * DD * 2);
  float*  simc   = (float*) alloc((size_t)CHUNK * NN * 4);

  zeroc_kernel<<<1, 128, 0, stream>>>(counters);

  // --- k-means init: JAX threefry choice(key, 8192, (64,), replace=False) ---
  rng_kernel<<<dim3(RR, 32), 256, 0, stream>>>(bits1, bits2);
  rankpart_kernel<<<dim3(RR, 32, 4), 256, 0, stream>>>(bits1, prank);
  scat1_kernel<<<dim3(RR, 32), 256, 0, stream>>>(prank, v1);
  rankpart_kernel<<<dim3(RR, 32, 4), 256, 0, stream>>>(bits2, prank);
  scat2_kernel<<<dim3(RR, 32), 256, 0, stream>>>(prank, v1, sel);
  init_cent_kernel<<<dim3(RR, CC), 256, 0, stream>>>(teacher, sel, centA, cnD, cnF, CHg, CLg);

  // --- pre-split inputs to hi/lo bf16 ---
  split_kernel<<<(NN * DD / 8) / 256, 256, 0, stream>>>(student, SH, SL);
  split_kernel<<<(NN * DD / 8) / 256, 256, 0, stream>>>(teacher, THi, TLo);

  // --- 20 Lloyd iterations: assign, batched fixup, hist, fill, update, norm ---
  double* cur = centA; double* nxt = centB;
  for (int it = 0; it < KM_ITERS; ++it) {
    assign_kernel<<<dim3(NN / 64, RR), 256, 0, stream>>>(THi, TLo, CHg, CLg, cnF,
                                                         labels, flags,
                                                         counters + it * RR);
    fixup_kernel<<<dim3(256, RR), 256, 0, stream>>>(teacher, cur, cnD, flags,
                                                    counters + it * RR, labels);
    hist_kernel<<<dim3(128, RR), 64, 0, stream>>>(labels, bhist, rib);
    fill_kernel<<<dim3(RR, 32), 256, 0, stream>>>(labels, rib, bhist, cstart, cnt, member);
    update_kernel<<<dim3(RR, CC, 8), 256, 0, stream>>>(teacher, member, cstart, cnt, cur, nxt);
    norm_kernel<<<dim3(RR, CC), 256, 0, stream>>>(nxt, cnD, cnF, CHg, CLg);
    double* t = cur; cur = nxt; nxt = t;
  }
  assign_kernel<<<dim3(NN / 64, RR), 256, 0, stream>>>(THi, TLo, CHg, CLg, cnF,
                                                       labels, flags,
                                                       counters + KM_ITERS * RR);
  fixup_kernel<<<dim3(256, RR), 256, 0, stream>>>(teacher, cur, cnD, flags,
                                                  counters + KM_ITERS * RR, labels);

  // --- sim = student @ teacher.T (+10 I), MFMA, 2 L3-resident chunks ---
  for (int ch = 0; ch < NN / CHUNK; ++ch) {
    gemm_kernel<<<dim3(NN / 128, CHUNK / 128), 256, 0, stream>>>(SH, SL, THi, TLo, simc,
                                                                 ch * CHUNK);
    topk_kernel<<<CHUNK, 256, 0, stream>>>(simc, student, teacher, iknn, ch * CHUNK);
  }

  // --- pos = 0 everywhere; pos[i, knn] = adj + mask ---
  zero_kernel<<<(unsigned)((size_t)NN * NN / 4 / 256), 256, 0, stream>>>((float4*)out);
  scatter_kernel<<<NN * TOPKK / 256, 256, 0, stream>>>(adj, iknn, labels, out);
}

// Round 10
// 2601.157 us; speedup vs baseline: 1.8089x; 1.8089x over previous
//
#include <hip/hip_runtime.h>
#include <stdint.h>

typedef unsigned int u32;
typedef unsigned long long u64;
typedef __attribute__((ext_vector_type(8))) short short8;
typedef __attribute__((ext_vector_type(4))) float f32x4;

#define NN 8192
#define DD 512
#define CC 64            // NUM_CENTROIDS
#define RR 5             // NUM_KMEANS
#define KM_ITERS 20
#define TOPKK 16
#define CHUNK 4096       // sim row-chunk (134 MB -> L3-resident)
#define GAP_TH 0.05f     // assign: f32 gap below which we re-decide in f64
#define FLAGTH 0.02f     // topk: margin16-17 below which row is resolved exactly
#define BAND_TH 0.01f    // resolve: band half-width around val16
#define FIXCAP (RR * NN) // flag capacity per iteration
#define TK_LO 256.0f     // linear bins cover [-256, 256) in steps of 1/8
#define TK_SCALE 8.0f

#define MFMA_BF16 __builtin_amdgcn_mfma_f32_16x16x32_bf16

// async global->LDS, 16B per lane; LDS dest = wave-uniform base + lane*16.
__device__ __forceinline__ void gload16(void* lds, const void* g) {
  __builtin_amdgcn_global_load_lds(
      (const __attribute__((address_space(1))) void*)g,
      (__attribute__((address_space(3))) void*)lds, 16, 0, 0);
}

// monotone key encode (exact total order on floats, desc-select by max)
__device__ __forceinline__ u32 keyenc(float v) {
  u32 u = __float_as_uint(v);
  return (u & 0x80000000u) ? ~u : (u | 0x80000000u);
}
// monotone linear bin; clamp keeps it monotone for out-of-range values
__device__ __forceinline__ int tkbin(float v) {
  int b = (int)((v + TK_LO) * TK_SCALE);
  return b < 0 ? 0 : (b > 4095 ? 4095 : b);
}

// ---------------- Threefry-2x32, 20 rounds (matches jax/_src/prng.py) -------
__device__ __forceinline__ void tf2x32(u32 k0, u32 k1, u32 x0, u32 x1,
                                       u32& o0, u32& o1) {
  u32 ks2 = k0 ^ k1 ^ 0x1BD11BDAu;
  x0 += k0; x1 += k1;
#define TFR(r) { x0 += x1; x1 = (x1 << r) | (x1 >> (32 - r)); x1 ^= x0; }
  TFR(13) TFR(15) TFR(26) TFR(6)
  x0 += k1; x1 += ks2 + 1u;
  TFR(17) TFR(29) TFR(16) TFR(24)
  x0 += ks2; x1 += k0 + 2u;
  TFR(13) TFR(15) TFR(26) TFR(6)
  x0 += k0; x1 += k1 + 3u;
  TFR(17) TFR(29) TFR(16) TFR(24)
  x0 += k1; x1 += ks2 + 4u;
  TFR(13) TFR(15) TFR(26) TFR(6)
  x0 += ks2; x1 += k0 + 5u;
#undef TFR
  o0 = x0; o1 = x1;
}

__global__ __launch_bounds__(256) void rng_kernel(u32* __restrict__ bits1,
                                                  u32* __restrict__ bits2) {
  int r = blockIdx.x;
  int i = blockIdx.y * 256 + threadIdx.x;
  u32 rk0, rk1; tf2x32(0u, 1234u, 0u, (u32)r, rk0, rk1);
  u32 k10, k11, s10, s11, s20, s21;
  tf2x32(rk0, rk1, 0u, 0u, k10, k11);
  tf2x32(rk0, rk1, 0u, 1u, s10, s11);
  tf2x32(k10, k11, 0u, 1u, s20, s21);
  u32 a, b;
  tf2x32(s10, s11, 0u, (u32)i, a, b);
  bits1[r * NN + i] = a ^ b;
  tf2x32(s20, s21, 0u, (u32)i, a, b);
  bits2[r * NN + i] = a ^ b;
}

__global__ __launch_bounds__(256) void rankpart_kernel(const u32* __restrict__ bits,
                                                       u32* __restrict__ prank) {
  __shared__ u64 sk[2048];
  int r = blockIdx.x, zc = blockIdx.z;
  const u32* bb = bits + (size_t)r * NN;
  int jbase = zc * 2048;
  for (int t = threadIdx.x; t < 2048; t += 256)
    sk[t] = ((u64)bb[jbase + t] << 13) | (u32)(jbase + t);
  __syncthreads();
  int i = blockIdx.y * 256 + threadIdx.x;
  u64 ki = ((u64)bb[i] << 13) | (u32)i;
  int cnt = 0;
#pragma unroll 8
  for (int j = 0; j < 2048; ++j) cnt += (int)(sk[j] < ki);
  prank[(size_t)(r * 4 + zc) * NN + i] = cnt;
}

__global__ __launch_bounds__(256) void scat1_kernel(const u32* __restrict__ prank,
                                                    int* __restrict__ vout) {
  int r = blockIdx.x;
  int i = blockIdx.y * 256 + threadIdx.x;
  int rank = prank[(size_t)(r * 4 + 0) * NN + i] + prank[(size_t)(r * 4 + 1) * NN + i] +
             prank[(size_t)(r * 4 + 2) * NN + i] + prank[(size_t)(r * 4 + 3) * NN + i];
  vout[(size_t)r * NN + rank] = i;
}

__global__ __launch_bounds__(256) void scat2_kernel(const u32* __restrict__ prank,
                                                    const int* __restrict__ v1,
                                                    int* __restrict__ sel) {
  int r = blockIdx.x;
  int i = blockIdx.y * 256 + threadIdx.x;
  int rank = prank[(size_t)(r * 4 + 0) * NN + i] + prank[(size_t)(r * 4 + 1) * NN + i] +
             prank[(size_t)(r * 4 + 2) * NN + i] + prank[(size_t)(r * 4 + 3) * NN + i];
  if (rank < CC) sel[r * CC + rank] = v1[(size_t)r * NN + i];
}

__device__ __forceinline__ double block_reduce_d(double s, double* red4) {
  int tid = threadIdx.x;
  for (int off = 32; off > 0; off >>= 1) s += __shfl_down(s, off, 64);
  if ((tid & 63) == 0) red4[tid >> 6] = s;
  __syncthreads();
  return red4[0] + red4[1] + red4[2] + red4[3];
}

// -------- bf16 split helpers --------
__device__ __forceinline__ u32 bf16rne(float a) {
  u32 ab = __float_as_uint(a);
  return (ab + 0x7FFFu + ((ab >> 16) & 1u)) >> 16;
}
__device__ __forceinline__ void splitf(float a, unsigned short& hi, unsigned short& lo) {
  u32 h = bf16rne(a);
  float hf = __uint_as_float(h << 16);
  hi = (unsigned short)h;
  lo = (unsigned short)bf16rne(a - hf);
}

// init centroids: f64 copy + norms + fused bf16 hi/lo split.
__global__ __launch_bounds__(256) void init_cent_kernel(const float* __restrict__ X,
                                                        const int* __restrict__ sel,
                                                        double* __restrict__ centD,
                                                        double* __restrict__ cnD,
                                                        float* __restrict__ cnF,
                                                        unsigned short* __restrict__ CHg,
                                                        unsigned short* __restrict__ CLg) {
  __shared__ double red4[4];
  int r = blockIdx.x, c = blockIdx.y, t = threadIdx.x;
  int src = sel[r * CC + c];
  const float* xp = X + (size_t)src * DD;
  size_t o = (size_t)(r * CC + c) * DD;
  double va = (double)xp[t], vb = (double)xp[t + 256];
  centD[o + t] = va; centD[o + t + 256] = vb;
  unsigned short h0, l0, h1, l1;
  splitf((float)va, h0, l0); splitf((float)vb, h1, l1);
  CHg[o + t] = h0; CLg[o + t] = l0;
  CHg[o + t + 256] = h1; CLg[o + t + 256] = l1;
  double tot = block_reduce_d(va * va + vb * vb, red4);
  if (t == 0) { cnD[r * CC + c] = tot; cnF[r * CC + c] = (float)tot; }
}

// Split an f32 array into hi/lo bf16 arrays. 8 elements per thread. (S/T only.)
__global__ __launch_bounds__(256) void split_kernel(const float* __restrict__ in,
                                                    unsigned short* __restrict__ hi,
                                                    unsigned short* __restrict__ lo) {
  size_t base = ((size_t)blockIdx.x * 256 + threadIdx.x) * 8;
  float4 v0 = *(const float4*)(in + base);
  float4 v1 = *(const float4*)(in + base + 4);
  float vv[8] = {v0.x, v0.y, v0.z, v0.w, v1.x, v1.y, v1.z, v1.w};
  unsigned short h[8], l[8];
#pragma unroll
  for (int j = 0; j < 8; ++j) splitf(vv[j], h[j], l[j]);
  uint4 hv, lv;
  hv.x = h[0] | ((u32)h[1] << 16); hv.y = h[2] | ((u32)h[3] << 16);
  hv.z = h[4] | ((u32)h[5] << 16); hv.w = h[6] | ((u32)h[7] << 16);
  lv.x = l[0] | ((u32)l[1] << 16); lv.y = l[2] | ((u32)l[3] << 16);
  lv.z = l[4] | ((u32)l[5] << 16); lv.w = l[6] | ((u32)l[7] << 16);
  *(uint4*)(hi + base) = hv;
  *(uint4*)(lo + base) = lv;
}

// MFMA assign: BK=64, global_load_lds staging. Labels + flag list out.
__global__ __launch_bounds__(256) void assign_kernel(const unsigned short* __restrict__ XH,
                                                     const unsigned short* __restrict__ XL,
                                                     const unsigned short* __restrict__ CHg,
                                                     const unsigned short* __restrict__ CLg,
                                                     const float* __restrict__ cnF,
                                                     int* __restrict__ labels,
                                                     u32* __restrict__ flags,
                                                     u32* __restrict__ counter) {
  __shared__ unsigned short Xh[2 * 64 * 32], Xl[2 * 64 * 32],
                            Ch[2 * 64 * 32], Cl[2 * 64 * 32];
  __shared__ float dmat[64 * 68];
  int r = blockIdx.y;
  int blk = blockIdx.x;
  int rowBase = blk * 64;
  int tid = threadIdx.x;
  int wid = tid >> 6, lane = tid & 63, m = lane & 15, q = lane >> 4;
  int srow = wid * 16 + (lane >> 2);
  int sslot = (lane & 3) * 8;                 // in shorts
  const unsigned short* gxh = XH + (size_t)(rowBase + srow) * DD + sslot;
  const unsigned short* gxl = XL + (size_t)(rowBase + srow) * DD + sslot;
  const unsigned short* gch = CHg + ((size_t)r * CC + srow) * DD + sslot;
  const unsigned short* gcl = CLg + ((size_t)r * CC + srow) * DD + sslot;
  f32x4 acc[4] = {};
  for (int kc = 0; kc < DD; kc += 64) {
#pragma unroll
    for (int p = 0; p < 2; ++p) {
      int off = p * 2048, ko = kc + p * 32;
      gload16(&Xh[off + wid * 512], gxh + ko);
      gload16(&Xl[off + wid * 512], gxl + ko);
      gload16(&Ch[off + wid * 512], gch + ko);
      gload16(&Cl[off + wid * 512], gcl + ko);
    }
    __syncthreads();
#pragma unroll
    for (int s = 0; s < 2; ++s) {
      int off = s * 2048;
      short8 ah = *(short8*)&Xh[off + (wid * 16 + m) * 32 + q * 8];
      short8 al = *(short8*)&Xl[off + (wid * 16 + m) * 32 + q * 8];
#pragma unroll
      for (int nt = 0; nt < 4; ++nt) {
        short8 bh = *(short8*)&Ch[off + (nt * 16 + m) * 32 + q * 8];
        short8 bl = *(short8*)&Cl[off + (nt * 16 + m) * 32 + q * 8];
        acc[nt] = MFMA_BF16(ah, bh, acc[nt], 0, 0, 0);
        acc[nt] = MFMA_BF16(ah, bl, acc[nt], 0, 0, 0);
        acc[nt] = MFMA_BF16(al, bh, acc[nt], 0, 0, 0);
      }
    }
    __syncthreads();
  }
#pragma unroll
  for (int nt = 0; nt < 4; ++nt) {
    float cn = cnF[r * CC + nt * 16 + m];
#pragma unroll
    for (int reg = 0; reg < 4; ++reg)
      dmat[(wid * 16 + q * 4 + reg) * 68 + nt * 16 + m] = cn - 2.0f * acc[nt][reg];
  }
  __syncthreads();
  if (tid < 64) {
    const float* dr = dmat + (size_t)tid * 68;
    float best = dr[0], second = 3.4e38f; int bi = 0;
    for (int c = 1; c < CC; ++c) {
      float v = dr[c];
      if (v < best) { second = best; best = v; bi = c; }
      else if (v < second) second = v;
    }
    labels[(size_t)r * NN + rowBase + tid] = bi;
    if (second - best < GAP_TH) {
      u32 idx = atomicAdd(counter, 1u);
      if (idx < FIXCAP) flags[idx] = (u32)(r * NN + rowBase + tid);
    }
  }
}

// Exact f64 re-decision for flagged rows. Grid-stride, 2048 blocks.
__global__ __launch_bounds__(256) void fixup_kernel(const float* __restrict__ X,
                                                    const double* __restrict__ centD,
                                                    const double* __restrict__ cnD,
                                                    const u32* __restrict__ flags,
                                                    const u32* __restrict__ counter,
                                                    int* __restrict__ labels) {
  __shared__ double darr[CC];
  int n = (int)*counter; if (n > FIXCAP) n = FIXCAP;
  int tid = threadIdx.x, c = tid >> 2, sub = tid & 3;
  for (int f = blockIdx.x; f < n; f += gridDim.x) {
    u32 pk = flags[f];
    int r = pk >> 13, i = pk & (NN - 1);
    const float* x = X + (size_t)i * DD + sub * 128;
    const double* cp = centD + (size_t)(r * CC + c) * DD + sub * 128;
    double s = 0.0;
    for (int k = 0; k < 128; ++k) s += (double)x[k] * cp[k];
    s += __shfl_down(s, 2, 64);
    s += __shfl_down(s, 1, 64);
    if (sub == 0) darr[c] = cnD[r * CC + c] - 2.0 * s;
    __syncthreads();
    if (tid == 0) {
      double best = darr[0]; int bi = 0;
      for (int cc = 1; cc < CC; ++cc) { double v = darr[cc]; if (v < best) { best = v; bi = cc; } }
      labels[(size_t)r * NN + i] = bi;
    }
    __syncthreads();
  }
}

// Per-64-row-group histogram + rank-in-group from corrected labels.
__global__ __launch_bounds__(64) void hist_kernel(const int* __restrict__ labels,
                                                  int* __restrict__ bhist,
                                                  int* __restrict__ rib) {
  __shared__ int labs[64];
  __shared__ int h[CC];
  int r = blockIdx.y, blk = blockIdx.x, tid = threadIdx.x;
  labs[tid] = labels[(size_t)r * NN + blk * 64 + tid];
  h[tid] = 0;
  __syncthreads();
  int lab = labs[tid];
  atomicAdd(&h[lab], 1);
  int rk = 0;
  for (int j = 0; j < tid; ++j) rk += (labs[j] == lab);
  rib[(size_t)r * NN + blk * 64 + tid] = rk;
  __syncthreads();
  bhist[(size_t)(r * 128 + blk) * CC + tid] = h[tid];
}

// fill fused with scan.
__global__ __launch_bounds__(256) void fill_kernel(const int* __restrict__ labels,
                                                   const int* __restrict__ rib,
                                                   const int* __restrict__ bhist,
                                                   int* __restrict__ cstart,
                                                   int* __restrict__ cnt,
                                                   int* __restrict__ member) {
  __shared__ int bh[128 * CC];
  __shared__ int cs[CC];
  __shared__ int tots[CC];
  int r = blockIdx.x, blk = blockIdx.y, tid = threadIdx.x;
  const int* src = bhist + (size_t)r * 128 * CC;
  for (int t = tid; t < 128 * CC; t += 256) bh[t] = src[t];
  __syncthreads();
  if (tid < CC) {
    int run = 0;
    for (int b = 0; b < 128; ++b) { int v = bh[b * CC + tid]; bh[b * CC + tid] = run; run += v; }
    tots[tid] = run;
  }
  __syncthreads();
  if (tid == 0) {
    int run = 0;
    for (int q2 = 0; q2 < CC; ++q2) { cs[q2] = run; run += tots[q2]; }
  }
  __syncthreads();
  int i = blk * 256 + tid;
  int lab = labels[(size_t)r * NN + i];
  int pos = cs[lab] + bh[(i >> 6) * CC + lab] + rib[(size_t)r * NN + i];
  member[(size_t)r * NN + pos] = i;
  if (blk == 0 && tid < CC) { cnt[r * CC + tid] = tots[tid]; cstart[r * CC + tid] = cs[tid]; }
}

__global__ __launch_bounds__(256) void update_kernel(const float* __restrict__ X,
                                                     const int* __restrict__ member,
                                                     const int* __restrict__ cstart,
                                                     const int* __restrict__ cnt,
                                                     const double* __restrict__ centOld,
                                                     double* __restrict__ centNew) {
  __shared__ double part[4][64];
  int r = blockIdx.x, c = blockIdx.y, dchunk = blockIdx.z;
  int tid = threadIdx.x;
  int d = dchunk * 64 + (tid & 63);
  int lane = tid >> 6;
  int n = cnt[r * CC + c];
  int st = cstart[r * CC + c];
  const int* mem = member + (size_t)r * NN + st;
  int n4 = (n + 3) >> 2;
  int lo = lane * n4;
  int hi = min(n, lo + n4);
  double s0 = 0, s1 = 0, s2 = 0, s3 = 0;
  int m = lo;
  for (; m + 3 < hi; m += 4) {
    s0 += (double)X[(size_t)mem[m + 0] * DD + d];
    s1 += (double)X[(size_t)mem[m + 1] * DD + d];
    s2 += (double)X[(size_t)mem[m + 2] * DD + d];
    s3 += (double)X[(size_t)mem[m + 3] * DD + d];
  }
  for (; m < hi; ++m) s0 += (double)X[(size_t)mem[m] * DD + d];
  part[lane][tid & 63] = (s0 + s1) + (s2 + s3);
  __syncthreads();
  if (tid < 64) {
    double tot = (part[0][tid] + part[1][tid]) + (part[2][tid] + part[3][tid]);
    size_t o = (size_t)(r * CC + c) * DD + dchunk * 64 + tid;
    double va = (n > 0) ? tot / (double)n : centOld[o];
    centNew[o] = va;
  }
}

// norm fused with centroid bf16 split.
__global__ __launch_bounds__(256) void norm_kernel(const double* __restrict__ centNew,
                                                   double* __restrict__ cnD,
                                                   float* __restrict__ cnF,
                                                   unsigned short* __restrict__ CHg,
                                                   unsigned short* __restrict__ CLg) {
  __shared__ double red4[4];
  int r = blockIdx.x, c = blockIdx.y, t = threadIdx.x;
  size_t o = (size_t)(r * CC + c) * DD;
  double va = centNew[o + t], vb = centNew[o + t + 256];
  unsigned short h0, l0, h1, l1;
  splitf((float)va, h0, l0); splitf((float)vb, h1, l1);
  CHg[o + t] = h0; CLg[o + t] = l0;
  CHg[o + t + 256] = h1; CLg[o + t + 256] = l1;
  double tot = block_reduce_d(va * va + vb * vb, red4);
  if (t == 0) { cnD[r * CC + c] = tot; cnF[r * CC + c] = (float)tot; }
}

// MFMA sim GEMM: 128x128 tile, 4 waves 2x2, bf16x3, BK=64,
// global_load_lds staging, bijective XCD swizzle.
__global__ __launch_bounds__(256) void gemm_kernel(const unsigned short* __restrict__ SH,
                                                   const unsigned short* __restrict__ SL,
                                                   const unsigned short* __restrict__ TH,
                                                   const unsigned short* __restrict__ TL,
                                                   float* __restrict__ sim,
                                                   int rowChunk) {
  __shared__ unsigned short Ah[2 * 128 * 32], Al[2 * 128 * 32],
                            Bh[2 * 128 * 32], Bl[2 * 128 * 32];
  int tid = threadIdx.x;
  int wid = tid >> 6, lane = tid & 63, m = lane & 15, q = lane >> 4;
  int waveM = wid >> 1, waveN = wid & 1;
  const int nwgx = NN / 128;                  // 64
  const int nwg = nwgx * (CHUNK / 128);       // 2048 (divisible by 8)
  int wg = blockIdx.y * nwgx + blockIdx.x;
  int swz = (wg & 7) * (nwg >> 3) + (wg >> 3);
  int rowTile = swz / nwgx, colTile = swz % nwgx;
  int rowBase = rowChunk + rowTile * 128;
  int colBase = colTile * 128;
  int sr0 = wid * 16 + (lane >> 2);
  int sr1 = (wid + 4) * 16 + (lane >> 2);
  int sslot = (lane & 3) * 8;                 // shorts
  const unsigned short* gah0 = SH + (size_t)(rowBase + sr0) * DD + sslot;
  const unsigned short* gah1 = SH + (size_t)(rowBase + sr1) * DD + sslot;
  const unsigned short* gal0 = SL + (size_t)(rowBase + sr0) * DD + sslot;
  const unsigned short* gal1 = SL + (size_t)(rowBase + sr1) * DD + sslot;
  const unsigned short* gbh0 = TH + (size_t)(colBase + sr0) * DD + sslot;
  const unsigned short* gbh1 = TH + (size_t)(colBase + sr1) * DD + sslot;
  const unsigned short* gbl0 = TL + (size_t)(colBase + sr0) * DD + sslot;
  const unsigned short* gbl1 = TL + (size_t)(colBase + sr1) * DD + sslot;
  f32x4 acc[4][4] = {};
  for (int kc = 0; kc < DD; kc += 64) {
#pragma unroll
    for (int p = 0; p < 2; ++p) {
      int off = p * 4096, ko = kc + p * 32;
      gload16(&Ah[off + wid * 512], gah0 + ko);
      gload16(&Ah[off + (wid + 4) * 512], gah1 + ko);
      gload16(&Al[off + wid * 512], gal0 + ko);
      gload16(&Al[off + (wid + 4) * 512], gal1 + ko);
      gload16(&Bh[off + wid * 512], gbh0 + ko);
      gload16(&Bh[off + (wid + 4) * 512], gbh1 + ko);
      gload16(&Bl[off + wid * 512], gbl0 + ko);
      gload16(&Bl[off + (wid + 4) * 512], gbl1 + ko);
    }
    __syncthreads();
#pragma unroll
    for (int s = 0; s < 2; ++s) {
      int off = s * 4096;
      short8 ah[4], al[4], bh[4], bl[4];
#pragma unroll
      for (int t = 0; t < 4; ++t) {
        ah[t] = *(short8*)&Ah[off + (waveM * 64 + t * 16 + m) * 32 + q * 8];
        al[t] = *(short8*)&Al[off + (waveM * 64 + t * 16 + m) * 32 + q * 8];
        bh[t] = *(short8*)&Bh[off + (waveN * 64 + t * 16 + m) * 32 + q * 8];
        bl[t] = *(short8*)&Bl[off + (waveN * 64 + t * 16 + m) * 32 + q * 8];
      }
#pragma unroll
      for (int mt = 0; mt < 4; ++mt)
#pragma unroll
        for (int nt = 0; nt < 4; ++nt) {
          acc[mt][nt] = MFMA_BF16(ah[mt], bh[nt], acc[mt][nt], 0, 0, 0);
          acc[mt][nt] = MFMA_BF16(ah[mt], bl[nt], acc[mt][nt], 0, 0, 0);
          acc[mt][nt] = MFMA_BF16(al[mt], bh[nt], acc[mt][nt], 0, 0, 0);
        }
    }
    __syncthreads();
  }
#pragma unroll
  for (int mt = 0; mt < 4; ++mt)
#pragma unroll
    for (int nt = 0; nt < 4; ++nt) {
      int gcol = colBase + waveN * 64 + nt * 16 + m;
#pragma unroll
      for (int reg = 0; reg < 4; ++reg) {
        int lrow = rowTile * 128 + waveM * 64 + mt * 16 + q * 4 + reg;
        int grow = rowChunk + lrow;
        float v = acc[mt][nt][reg];
        if (grow == gcol) v += 10.0f;
        sim[(size_t)lrow * NN + gcol] = v;
      }
    }
}

// ---- top-16 via single-level LINEAR-bin select + fused exact resolve.
__global__ __launch_bounds__(256) void topk_kernel(const float* __restrict__ sim,
                                                   const float* __restrict__ S,
                                                   const float* __restrict__ T,
                                                   int* __restrict__ iknn,
                                                   int rowChunk) {
  __shared__ int bins[4096];      // 16 KB
  __shared__ int partial[256];
  __shared__ u64 cand[128];
  __shared__ u64 sure[24];        // provably <=16 used
  __shared__ u64 outk[TOPKK + 1];
  __shared__ u64 red[4];
  __shared__ int nsure, ncand, selB1, hardcase;
  __shared__ int nsureR, nbandR;
  __shared__ int sidx[16];
  __shared__ int bidx[64];
  __shared__ double bval[64];

  int blk = blockIdx.x, tid = threadIdx.x;
  int grow = rowChunk + blk;
  const float* rp = sim + (size_t)blk * NN;

  for (int t = tid; t < 4096; t += 256) bins[t] = 0;
  if (tid == 0) { nsure = 0; ncand = 0; hardcase = 0; }
  __syncthreads();
  for (int t = tid; t < NN; t += 256) atomicAdd(&bins[tkbin(rp[t])], 1);
  __syncthreads();
  int ps = 0;
#pragma unroll
  for (int b = 0; b < 16; ++b) ps += bins[tid * 16 + b];
  partial[tid] = ps;
  __syncthreads();
  if (tid == 0) {
    int cum = 0, c = 255;
    for (; c > 0; --c) { if (cum + partial[c] >= 17) break; cum += partial[c]; }
    int b = c * 16 + 15;
    for (; b > c * 16; --b) { if (cum + bins[b] >= 17) break; cum += bins[b]; }
    selB1 = b;
  }
  __syncthreads();
  int B1 = selB1;
  for (int t = tid; t < NN; t += 256) {
    float v = rp[t];
    int b = tkbin(v);
    if (b < B1) continue;
    u64 key = ((u64)keyenc(v) << 32) | (u32)(NN - 1 - t);
    if (b > B1) { int s = atomicAdd(&nsure, 1); if (s < 24) sure[s] = key; }
    else        { int s = atomicAdd(&ncand, 1); if (s < 128) cand[s] = key; }
  }
  __syncthreads();
  if (tid == 0 && ncand > 128) hardcase = 1;
  __syncthreads();
  if (!hardcase) {
    int ns = nsure, nc = ncand;
    int total = ns + nc;
    if (tid < total) {
      u64 k = tid < ns ? sure[tid] : cand[tid - ns];
      int rank = 0;
      for (int j = 0; j < total; ++j) {
        u64 o = j < ns ? sure[j] : cand[j - ns];
        rank += (int)(o > k);
      }
      if (rank < TOPKK + 1) outk[rank] = k;
    }
    __syncthreads();
  } else {
    for (int k = 0; k < TOPKK + 1; ++k) {
      u64 best = 0;
      for (int t = tid; t < NN; t += 256) {
        u64 key = ((u64)keyenc(rp[t]) << 32) | (u32)(NN - 1 - t);
        bool excl = false;
        for (int j = 0; j < k; ++j) excl |= (outk[j] == key);
        if (!excl && key > best) best = key;
      }
      for (int off = 32; off > 0; off >>= 1) {
        u32 lo = (u32)best, hi = (u32)(best >> 32);
        lo = __shfl_down(lo, off, 64); hi = __shfl_down(hi, off, 64);
        u64 o = ((u64)hi << 32) | lo;
        best = o > best ? o : best;
      }
      if ((tid & 63) == 0) red[tid >> 6] = best;
      __syncthreads();
      if (tid == 0) {
        u64 b = red[0];
        for (int w = 1; w < 4; ++w) b = red[w] > b ? red[w] : b;
        outk[k] = b;
      }
      __syncthreads();
    }
  }
  if (tid < TOPKK)
    iknn[(size_t)grow * TOPKK + tid] = (NN - 1) - (int)(outk[tid] & 0xFFFFFFFFu);
  u32 ub16 = (u32)(outk[TOPKK - 1] >> 32), ub17 = (u32)(outk[TOPKK] >> 32);
  float v16 = (ub16 & 0x80000000u) ? __uint_as_float(ub16 & 0x7FFFFFFFu)
                                   : __uint_as_float(~ub16);
  float v17 = (ub17 & 0x80000000u) ? __uint_as_float(ub17 & 0x7FFFFFFFu)
                                   : __uint_as_float(~ub17);
  if (v16 - v17 >= FLAGTH) return;

  // ---- fused exact resolve (marginal rows only; same math as before) ----
  if (tid == 0) { nsureR = 0; nbandR = 0; }
  __syncthreads();
  for (int j = tid; j < NN; j += 256) {
    float v = rp[j];
    if (v > v16 + BAND_TH) {
      int s = atomicAdd(&nsureR, 1);
      if (s < 16) sidx[s] = j;
    } else if (v >= v16 - BAND_TH) {
      int s = atomicAdd(&nbandR, 1);
      if (s < 64) bidx[s] = j;
    }
  }
  __syncthreads();
  int nb = nbandR > 64 ? 64 : nbandR;
  if (tid < nb) {
    const float* sp = S + (size_t)grow * DD;
    const float* tp = T + (size_t)bidx[tid] * DD;
    double s = 0.0;
    for (int k = 0; k < DD; ++k) s += (double)sp[k] * (double)tp[k];
    bval[tid] = s;
  }
  __syncthreads();
  if (tid == 0) {
    int w = 0;
    int ns = nsureR < 16 ? nsureR : 16;
    for (int i2 = 0; i2 < ns; ++i2) iknn[(size_t)grow * TOPKK + w++] = sidx[i2];
    u64 used = 0;
    while (w < TOPKK) {
      int bj = -1; double bv = 0.0;
      for (int i2 = 0; i2 < nb; ++i2) {
        if (used & (1ull << i2)) continue;
        if (bj < 0 || bval[i2] > bv ||
            (bval[i2] == bv && bidx[i2] < bidx[bj])) { bv = bval[i2]; bj = i2; }
      }
      if (bj < 0) break;
      used |= 1ull << bj;
      iknn[(size_t)grow * TOPKK + w++] = bidx[bj];
    }
  }
}

__global__ __launch_bounds__(256) void zero_kernel(float4* __restrict__ out) {
  size_t i = (size_t)blockIdx.x * 256 + threadIdx.x;
  out[i] = make_float4(0.f, 0.f, 0.f, 0.f);
}

__global__ void zeroc_kernel(u32* __restrict__ c) {
  c[threadIdx.x] = 0u;   // 64 counters
}

__global__ __launch_bounds__(256) void scatter_kernel(const float* __restrict__ adj,
                                                      const int* __restrict__ iknn,
                                                      const int* __restrict__ labels,
                                                      float* __restrict__ out) {
  int idx = blockIdx.x * 256 + threadIdx.x;
  int i = idx >> 4;
  int col = iknn[idx];
  int m = 0;
#pragma unroll
  for (int r = 0; r < RR; ++r)
    m |= (labels[(size_t)r * NN + i] == labels[(size_t)r * NN + col]);
  size_t o = (size_t)i * NN + col;
  out[o] = adj[o] + (float)m;
}

extern "C" void kernel_launch(void* const* d_in, const int* in_sizes, int n_in,
                              void* d_out, int out_size, void* d_ws, size_t ws_size,
                              hipStream_t stream) {
  (void)in_sizes; (void)n_in; (void)out_size; (void)ws_size;
  const float* adj     = (const float*)d_in[0];
  const float* student = (const float*)d_in[1];
  const float* teacher = (const float*)d_in[2];
  float* out = (float*)d_out;

  char* p = (char*)d_ws;
  auto alloc = [&](size_t bytes) -> void* {
    void* q = (void*)p; p += (bytes + 255) & ~(size_t)255; return q;
  };
  double* centA  = (double*)alloc((size_t)RR * CC * DD * 8);
  double* centB  = (double*)alloc((size_t)RR * CC * DD * 8);
  double* cnD    = (double*)alloc((size_t)RR * CC * 8);
  float*  cnF    = (float*) alloc((size_t)RR * CC * 4);
  u32*    bits1  = (u32*)   alloc((size_t)RR * NN * 4);
  u32*    bits2  = (u32*)   alloc((size_t)RR * NN * 4);
  u32*    prank  = (u32*)   alloc((size_t)RR * 4 * NN * 4);
  int*    v1     = (int*)   alloc((size_t)RR * NN * 4);
  int*    sel    = (int*)   alloc((size_t)RR * CC * 4);
  int*    labels = (int*)   alloc((size_t)RR * NN * 4);
  int*    bhist  = (int*)   alloc((size_t)RR * 128 * CC * 4);
  int*    cstart = (int*)   alloc((size_t)RR * CC * 4);
  int*    cnt    = (int*)   alloc((size_t)RR * CC * 4);
  int*    rib    = (int*)   alloc((size_t)RR * NN * 4);
  int*    member = (int*)   alloc((size_t)RR * NN * 4);
  u32*    flags  = (u32*)   alloc((size_t)FIXCAP * 4);
  u32*    counters = (u32*) alloc((size_t)64 * 4);
  int*    iknn   = (int*)   alloc((size_t)NN * TOPKK * 4);
  unsigned short* SH = (unsigned short*)alloc((size_t)NN * DD * 2);
  unsigned short* SL = (unsigned short*)alloc((size_t)NN * DD * 2);
  unsigned short* THi = (unsigned short*)alloc((size_t)NN * DD * 2);
  unsigned short* TLo = (unsigned short*)alloc((size_t)NN * DD * 2);
  unsigned short* CHg = (unsigned short*)alloc((size_t)RR * CC * DD * 2);
  unsigned short* CLg = (unsigned short*)alloc((size_t)RR * CC * DD * 2);
  float*  simc   = (float*) alloc((size_t)CHUNK * NN * 4);

  zeroc_kernel<<<1, 64, 0, stream>>>(counters);

  // --- k-means init: JAX threefry choice(key, 8192, (64,), replace=False) ---
  rng_kernel<<<dim3(RR, 32), 256, 0, stream>>>(bits1, bits2);
  rankpart_kernel<<<dim3(RR, 32, 4), 256, 0, stream>>>(bits1, prank);
  scat1_kernel<<<dim3(RR, 32), 256, 0, stream>>>(prank, v1);
  rankpart_kernel<<<dim3(RR, 32, 4), 256, 0, stream>>>(bits2, prank);
  scat2_kernel<<<dim3(RR, 32), 256, 0, stream>>>(prank, v1, sel);
  init_cent_kernel<<<dim3(RR, CC), 256, 0, stream>>>(teacher, sel, centA, cnD, cnF, CHg, CLg);

  // --- pre-split inputs to hi/lo bf16 ---
  split_kernel<<<(NN * DD / 8) / 256, 256, 0, stream>>>(student, SH, SL);
  split_kernel<<<(NN * DD / 8) / 256, 256, 0, stream>>>(teacher, THi, TLo);

  // --- 20 Lloyd iterations: assign, parallel fixup, hist, fill, update, norm ---
  double* cur = centA; double* nxt = centB;
  for (int it = 0; it < KM_ITERS; ++it) {
    assign_kernel<<<dim3(NN / 64, RR), 256, 0, stream>>>(THi, TLo, CHg, CLg, cnF,
                                                         labels, flags, counters + it);
    fixup_kernel<<<2048, 256, 0, stream>>>(teacher, cur, cnD, flags, counters + it, labels);
    hist_kernel<<<dim3(128, RR), 64, 0, stream>>>(labels, bhist, rib);
    fill_kernel<<<dim3(RR, 32), 256, 0, stream>>>(labels, rib, bhist, cstart, cnt, member);
    update_kernel<<<dim3(RR, CC, 8), 256, 0, stream>>>(teacher, member, cstart, cnt, cur, nxt);
    norm_kernel<<<dim3(RR, CC), 256, 0, stream>>>(nxt, cnD, cnF, CHg, CLg);
    double* t = cur; cur = nxt; nxt = t;
  }
  assign_kernel<<<dim3(NN / 64, RR), 256, 0, stream>>>(THi, TLo, CHg, CLg, cnF,
                                                       labels, flags, counters + KM_ITERS);
  fixup_kernel<<<2048, 256, 0, stream>>>(teacher, cur, cnD, flags,
                                         counters + KM_ITERS, labels);

  // --- sim = student @ teacher.T (+10 I), MFMA, 2 L3-resident chunks ---
  for (int ch = 0; ch < NN / CHUNK; ++ch) {
    gemm_kernel<<<dim3(NN / 128, CHUNK / 128), 256, 0, stream>>>(SH, SL, THi, TLo, simc,
                                                                 ch * CHUNK);
    topk_kernel<<<CHUNK, 256, 0, stream>>>(simc, student, teacher, iknn, ch * CHUNK);
  }

  // --- pos = 0 everywhere; pos[i, knn] = adj + mask ---
  zero_kernel<<<(unsigned)((size_t)NN * NN / 4 / 256), 256, 0, stream>>>((float4*)out);
  scatter_kernel<<<NN * TOPKK / 256, 256, 0, stream>>>(adj, iknn, labels, out);
}